// Round 5
// baseline (538.335 us; speedup 1.0000x reference)
//
#include <hip/hip_runtime.h>
#include <hip/hip_bf16.h>

typedef short bf16x8 __attribute__((ext_vector_type(8)));
typedef float f32x4  __attribute__((ext_vector_type(4)));

#define H_NODE 64
#define H_EDGE 128
#define IN_DIM 256
#define WAVES  12
#define BLOCK  768
#define GRID   256
#define LN_EPS 1e-5f

// Static LDS layout (byte offsets), 144 KiB (1 block/CU):
//   [0,      65536): W1^T bf16: addr = col*512 + ((k*2) ^ ((col&7)<<4)),  col in [0,128), k in [0,256)
//   [65536,  98304): W2^T bf16: addr = 65536 + col*256 + ((k*2) ^ ((col&7)<<4)), k in [0,128)
//   [98304, 147456): per-wave transpose tile (16 rows x 128 bf16, 4KB x 12 waves)
//
// Round-5: round-3 structure (262us champion) with 12 waves instead of 8.
//   - BLOCK=768, __launch_bounds__(768,3) -> 170 VGPR/wave cap, 3 waves/SIMD
//     (round-3's 2/SIMD left the LDS pipe idle ~50% while phase-aligned waves
//     sat in VALU/latency phases together).
//   - To fit 170: acc shared between GEMM1/GEMM2 (round-2, proven spill-free)
//     and bias/gamma/beta reloaded per tile from L1-hot lines (b1 under GEMM1
//     cover; LN consts after GEMM2) instead of persistent. Peak live ~158.
//   - Full 1-tile-deep register staging of node+edge gathers kept verbatim.
//   - Round-4's residual-reload REVERTED (L2 lifetime of stream data < 1 tile:
//     FETCH +88MB and exposed L3/HBM latency on the LN path). w goes back
//     through the per-wave LDS tile; residual comes from A1[4..7] registers.
// Spill tripwire: WRITE_SIZE > 600 MB -> fallback: JIT-edge (-32 staging regs).

static __device__ __forceinline__ short f2bf(float x) {
    __hip_bfloat16 h = __float2bfloat16(x);   // RNE
    return *reinterpret_cast<short*>(&h);
}

static __device__ __forceinline__ float bf2f(short s) {
    union { unsigned int u; float f; } v;
    v.u = ((unsigned int)(unsigned short)s) << 16;
    return v.f;
}

static __device__ __forceinline__ int tswz(int r, int g) {
    return r * 256 + ((g ^ ((r >> 2) << 1)) << 4);
}

static __device__ __forceinline__ bf16x8 cvt8(f32x4 lo, f32x4 hi) {
    bf16x8 f;
    f[0] = f2bf(lo[0]); f[1] = f2bf(lo[1]); f[2] = f2bf(lo[2]); f[3] = f2bf(lo[3]);
    f[4] = f2bf(hi[0]); f[5] = f2bf(hi[1]); f[6] = f2bf(hi[2]); f[7] = f2bf(hi[3]);
    return f;
}

extern "C" __global__ void __launch_bounds__(BLOCK, 3)
edge_update(const float* __restrict__ node,
            const float* __restrict__ edgef,
            const int* __restrict__ ei,          // int32 on device
            const float* __restrict__ W1, const float* __restrict__ b1,
            const float* __restrict__ W2, const float* __restrict__ b2,
            const float* __restrict__ gamma, const float* __restrict__ beta,
            float* __restrict__ out, int E)
{
    __shared__ char lds[147456];
    const int tid = threadIdx.x;

    // ---- stage W1^T (bf16, swizzled) ----
    for (int e = tid; e < 32768; e += BLOCK) {   // W1 is [k][n], k<256, n<128
        int k = e >> 7, n = e & 127;
        float v = W1[e];
        int addr = n * 512 + ((k * 2) ^ ((n & 7) << 4));
        *(short*)(lds + addr) = f2bf(v);
    }
    // ---- stage W2^T ----
    for (int e = tid; e < 16384; e += BLOCK) {   // W2 is [k][n], k<128, n<128
        int k = e >> 7, n = e & 127;
        float v = W2[e];
        int addr = 65536 + n * 256 + ((k * 2) ^ ((n & 7) << 4));
        *(short*)(lds + addr) = f2bf(v);
    }
    __syncthreads();

    const int wid   = tid >> 6;
    const int lane  = tid & 63;
    const int lrow  = lane & 15;   // A-frag row / C col / B col
    const int lk8   = lane >> 4;   // k-subchunk 0..3
    const int hbase = 98304 + wid * 4096;

    // one-time phase stagger (~1.5k cycles per wave id): de-align LDS bursts
    for (int i = 0; i < wid; ++i) __builtin_amdgcn_s_sleep(24);

    const int ntiles  = (E + 15) >> 4;
    const int wstride = GRID * WAVES;

    int tile = blockIdx.x * WAVES + wid;
    if (tile >= ntiles) return;

    // ---- prologue: indices + staged gather for tile t; indices for t+1 ----
    int rowg = tile * 16 + lrow; if (rowg >= E) rowg = E - 1;
    int sidx = ei[rowg];
    int didx = ei[E + rowg];

    f32x4 Sn0, Sn1, Sn2, Sn3, Sn4, Sn5, Sn6, Sn7;   // node src/dst raw
    f32x4 Se0, Se1, Se2, Se3, Se4, Se5, Se6, Se7;   // edge row raw
    {
        const float* sp = node + (size_t)sidx * H_NODE + lk8 * 8;
        const float* dp = node + (size_t)didx * H_NODE + lk8 * 8;
        const float* ep = edgef + (size_t)rowg * H_EDGE + lk8 * 8;
        Sn0 = *(const f32x4*)(sp);      Sn1 = *(const f32x4*)(sp + 4);
        Sn2 = *(const f32x4*)(sp + 32); Sn3 = *(const f32x4*)(sp + 36);
        Sn4 = *(const f32x4*)(dp);      Sn5 = *(const f32x4*)(dp + 4);
        Sn6 = *(const f32x4*)(dp + 32); Sn7 = *(const f32x4*)(dp + 36);
        Se0 = *(const f32x4*)(ep);      Se1 = *(const f32x4*)(ep + 4);
        Se2 = *(const f32x4*)(ep + 32); Se3 = *(const f32x4*)(ep + 36);
        Se4 = *(const f32x4*)(ep + 64); Se5 = *(const f32x4*)(ep + 68);
        Se6 = *(const f32x4*)(ep + 96); Se7 = *(const f32x4*)(ep + 100);
    }
    int next  = tile + wstride;
    int nrowg = next * 16 + lrow; if (nrowg >= E) nrowg = E - 1;
    int nsidx = ei[nrowg];
    int ndidx = ei[E + nrowg];

    while (tile < ntiles) {
        // ---- fold staged gather (issued one full tile ago) into A1 ----
        bf16x8 A1[8];
        A1[0] = cvt8(Sn0, Sn1);
        A1[1] = cvt8(Sn2, Sn3);
        A1[2] = cvt8(Sn4, Sn5);
        A1[3] = cvt8(Sn6, Sn7);
        A1[4] = cvt8(Se0, Se1);
        A1[5] = cvt8(Se2, Se3);
        A1[6] = cvt8(Se4, Se5);
        A1[7] = cvt8(Se6, Se7);

        // ---- issue NEXT tile's FULL gather burst (in flight all tile) ----
        {
            const float* sp = node + (size_t)nsidx * H_NODE + lk8 * 8;
            const float* dp = node + (size_t)ndidx * H_NODE + lk8 * 8;
            const float* ep = edgef + (size_t)nrowg * H_EDGE + lk8 * 8;
            Sn0 = *(const f32x4*)(sp);      Sn1 = *(const f32x4*)(sp + 4);
            Sn2 = *(const f32x4*)(sp + 32); Sn3 = *(const f32x4*)(sp + 36);
            Sn4 = *(const f32x4*)(dp);      Sn5 = *(const f32x4*)(dp + 4);
            Sn6 = *(const f32x4*)(dp + 32); Sn7 = *(const f32x4*)(dp + 36);
            Se0 = *(const f32x4*)(ep);      Se1 = *(const f32x4*)(ep + 4);
            Se2 = *(const f32x4*)(ep + 32); Se3 = *(const f32x4*)(ep + 36);
            Se4 = *(const f32x4*)(ep + 64); Se5 = *(const f32x4*)(ep + 68);
            Se6 = *(const f32x4*)(ep + 96); Se7 = *(const f32x4*)(ep + 100);
        }
        // ---- prefetch tile+2 indices ----
        int t2 = next + wstride;
        int t2rowg = t2 * 16 + lrow; if (t2rowg >= E) t2rowg = E - 1;
        int t2s = ei[t2rowg];
        int t2d = ei[E + t2rowg];

        // ---- b1 reload (L1-hot broadcast lines; latency covered by GEMM1) ----
        float b1v[8];
        #pragma unroll
        for (int n = 0; n < 8; ++n) b1v[n] = b1[n * 16 + lrow];

        // ---- GEMM1: [16x256] @ [256x128] ----
        f32x4 acc[8];
        #pragma unroll
        for (int n = 0; n < 8; ++n) acc[n] = (f32x4){0.f, 0.f, 0.f, 0.f};
        #pragma unroll
        for (int n = 0; n < 8; ++n) {
            const int col = n * 16 + lrow;
            const int cb  = col * 512;
            const int sw  = (col & 7) << 4;
            #pragma unroll
            for (int t = 0; t < 8; ++t) {
                int kb = t * 64 + lk8 * 16;
                bf16x8 bfrag = *(const bf16x8*)(lds + cb + (kb ^ sw));
                acc[n] = __builtin_amdgcn_mfma_f32_16x16x32_bf16(A1[t], bfrag, acc[n], 0, 0, 0);
            }
        }

        // ---- bias + relu -> h (bf16) to per-wave LDS (conflict-free swizzle) ----
        #pragma unroll
        for (int n = 0; n < 8; ++n) {
            const int g = n * 2 + (lrow >> 3);
            const int cl = (lrow & 7) * 2;
            #pragma unroll
            for (int i = 0; i < 4; ++i) {
                float u = fmaxf(acc[n][i] + b1v[n], 0.f);
                int row = lk8 * 4 + i;
                *(short*)(lds + hbase + tswz(row, g) + cl) = f2bf(u);
            }
        }
        // same-wave cross-lane LDS visibility: drain ds_writes before reads
        asm volatile("s_waitcnt lgkmcnt(0)" ::: "memory");

        // ---- GEMM2: [16x128] @ [128x128], REUSING acc (saves 32 AGPR) ----
        bf16x8 A2[4];
        #pragma unroll
        for (int t = 0; t < 4; ++t)
            A2[t] = *(const bf16x8*)(lds + hbase + tswz(lrow, t * 4 + lk8));

        #pragma unroll
        for (int n = 0; n < 8; ++n) acc[n] = (f32x4){0.f, 0.f, 0.f, 0.f};
        #pragma unroll
        for (int n = 0; n < 8; ++n) {
            const int col = n * 16 + lrow;
            const int cb  = 65536 + col * 256;
            const int sw  = (col & 7) << 4;
            #pragma unroll
            for (int t = 0; t < 4; ++t) {
                int kb = t * 64 + lk8 * 16;
                bf16x8 bfrag = *(const bf16x8*)(lds + cb + (kb ^ sw));
                acc[n] = __builtin_amdgcn_mfma_f32_16x16x32_bf16(A2[t], bfrag, acc[n], 0, 0, 0);
            }
        }

        // ---- LN constants reload (L1-hot, once per tile) ----
        float b2v[8], gv[8], btv[8];
        #pragma unroll
        for (int n = 0; n < 8; ++n) {
            int c = n * 16 + lrow;
            b2v[n] = b2[c]; gv[n] = gamma[c]; btv[n] = beta[c];
        }

        // ---- bias2 + LayerNorm (C-layout) -> w (bf16) back through LDS ----
        #pragma unroll
        for (int i = 0; i < 4; ++i) {
            float u[8];
            float s = 0.f, sq = 0.f;
            #pragma unroll
            for (int n = 0; n < 8; ++n) {
                u[n] = acc[n][i] + b2v[n];
                s  += u[n];
                sq += u[n] * u[n];
            }
            #pragma unroll
            for (int m = 1; m < 16; m <<= 1) {
                s  += __shfl_xor(s,  m, 64);
                sq += __shfl_xor(sq, m, 64);
            }
            float mu  = s * (1.f / 128.f);
            float var = sq * (1.f / 128.f) - mu * mu;
            float rs  = rsqrtf(var + LN_EPS);
            int row = lk8 * 4 + i;
            const int cl = (lrow & 7) * 2;
            #pragma unroll
            for (int n = 0; n < 8; ++n) {
                float w = (u[n] - mu) * rs * gv[n] + btv[n];
                *(short*)(lds + hbase + tswz(row, n * 2 + (lrow >> 3)) + cl) = f2bf(w);
            }
        }
        asm volatile("s_waitcnt lgkmcnt(0)" ::: "memory");

        // ---- read w in A-layout, residual from registers, coalesced store ----
        {
            int row = tile * 16 + lrow;
            if (row < E) {
                float* orow = out + (size_t)row * H_EDGE;
                #pragma unroll
                for (int t = 0; t < 4; ++t) {
                    bf16x8 wf = *(const bf16x8*)(lds + hbase + tswz(lrow, t * 4 + lk8));
                    bf16x8 ef = A1[t + 4];
                    float4 lo, hi;
                    lo.x = bf2f(wf[0]) + bf2f(ef[0]);
                    lo.y = bf2f(wf[1]) + bf2f(ef[1]);
                    lo.z = bf2f(wf[2]) + bf2f(ef[2]);
                    lo.w = bf2f(wf[3]) + bf2f(ef[3]);
                    hi.x = bf2f(wf[4]) + bf2f(ef[4]);
                    hi.y = bf2f(wf[5]) + bf2f(ef[5]);
                    hi.z = bf2f(wf[6]) + bf2f(ef[6]);
                    hi.w = bf2f(wf[7]) + bf2f(ef[7]);
                    float* dst = orow + t * 32 + lk8 * 8;
                    *(float4*)dst       = lo;
                    *(float4*)(dst + 4) = hi;
                }
            }
        }

        // ---- rotate pipeline state ----
        tile = next;  next = t2;
        nrowg = t2rowg; nsidx = t2s; ndidx = t2d;
    }
}

extern "C" void kernel_launch(void* const* d_in, const int* in_sizes, int n_in,
                              void* d_out, int out_size, void* d_ws, size_t ws_size,
                              hipStream_t stream) {
    const float* node  = (const float*)d_in[0];
    const float* edgef = (const float*)d_in[1];
    const int*   ei    = (const int*)d_in[2];    // int32 on device
    const float* W1    = (const float*)d_in[3];
    const float* b1    = (const float*)d_in[4];
    const float* W2    = (const float*)d_in[5];
    const float* b2    = (const float*)d_in[6];
    const float* gamma = (const float*)d_in[7];
    const float* beta  = (const float*)d_in[8];
    float* outp = (float*)d_out;
    const int E = in_sizes[2] / 2;   // edge_index is [2, E]

    hipLaunchKernelGGL(edge_update, dim3(GRID), dim3(BLOCK), 0, stream,
                       node, edgef, ei, W1, b1, W2, b2, gamma, beta, outp, E);
}

// Round 6
// 420.173 us; speedup vs baseline: 1.2812x; 1.2812x over previous
//
#include <hip/hip_runtime.h>
#include <hip/hip_bf16.h>

typedef short bf16x8 __attribute__((ext_vector_type(8)));
typedef short bf16x4 __attribute__((ext_vector_type(4)));
typedef float f32x4  __attribute__((ext_vector_type(4)));

#define H_NODE 64
#define H_EDGE 128
#define WAVES  8
#define BLOCK  512
#define GRID   256
#define LN_EPS 1e-5f

// Static LDS layout (byte offsets), 128 KiB (1 block/CU):
//   [0,      65536): W1^T bf16, COLUMN-PERMUTED into "slots":
//       slot s of col c: s = [c6 c5 c2 c4 c3 c1 c0]  (bit shuffle)
//       addr = slot*512 + ((k*2) ^ ((slot&7)<<4))
//   [65536,  98304): W2^T bf16 (unpermuted): addr = 65536 + col*256 + ((k*2)^((col&7)<<4))
//   [98304, 131072): per-wave residual tile (16 rows x 128 bf16, 4KB x 8 waves)
//
// Round-6: SWAPPED-OPERAND MFMA (mfma(Wfrag, xfrag)) -> outputs land transposed,
// each lane owns its edge row's slice:
//   GEMM1 chunk q gives lane (lrow,lk8): h[r0+lrow][pi(q, lk8*4+i)],
//   pi(q,m) = (q>>1)*32 + (m>>2)*8 + (q&1)*4 + (m&3)  -- the W1 col permutation
//   is chosen so that bias+relu+pack yields GEMM2's B-fragments LANE-LOCALLY
//   (no h LDS round-trip, no shuffles). GEMM2 output is row-owned: LN reduce =
//   64 local adds + 2 shfl_xor pairs (vs 32 shfl), 1 rsqrt (vs 4), and w is
//   stored DIRECTLY as float4 (16 rows x 64B segments, no w LDS round-trip).
// Residual: edge B-frags written once to the per-wave tile at tile top
// (4 ds_write_b128), re-read at store time in store layout (8 ds_read_b64).
// Consts (b1 permuted, b2, gamma, beta) persistent as packed bf16 (64 dwords).
// Keeps round-3's proven 8-wave / full 1-tile-deep register gather staging.
// Spill tripwire: WRITE_SIZE > 600 MB.

static __device__ __forceinline__ short f2bf(float x) {
    __hip_bfloat16 h = __float2bfloat16(x);   // RNE
    return *reinterpret_cast<short*>(&h);
}

static __device__ __forceinline__ float bf2f(short s) {
    union { unsigned int u; float f; } v;
    v.u = ((unsigned int)(unsigned short)s) << 16;
    return v.f;
}

static __device__ __forceinline__ unsigned int pk2(float x, float y) {
    return ((unsigned int)(unsigned short)f2bf(x)) |
           (((unsigned int)(unsigned short)f2bf(y)) << 16);
}

static __device__ __forceinline__ float upk(unsigned int u, int hi) {
    union { unsigned int b; float f; } v;
    v.b = hi ? (u & 0xffff0000u) : (u << 16);
    return v.f;
}

static __device__ __forceinline__ bf16x8 cvt8(f32x4 lo, f32x4 hi) {
    bf16x8 f;
    f[0] = f2bf(lo[0]); f[1] = f2bf(lo[1]); f[2] = f2bf(lo[2]); f[3] = f2bf(lo[3]);
    f[4] = f2bf(hi[0]); f[5] = f2bf(hi[1]); f[6] = f2bf(hi[2]); f[7] = f2bf(hi[3]);
    return f;
}

extern "C" __global__ void __launch_bounds__(BLOCK, 2)
edge_update(const float* __restrict__ node,
            const float* __restrict__ edgef,
            const int* __restrict__ ei,          // int32 on device
            const float* __restrict__ W1, const float* __restrict__ b1,
            const float* __restrict__ W2, const float* __restrict__ b2,
            const float* __restrict__ gamma, const float* __restrict__ beta,
            float* __restrict__ out, int E)
{
    __shared__ char lds[131072];
    const int tid = threadIdx.x;

    // ---- stage W1^T (bf16, column slot-permuted, swizzled) ----
    for (int e = tid; e < 32768; e += BLOCK) {   // W1 is [k][c], k<256, c<128
        int k = e >> 7, c = e & 127;
        // slot bits: [c6 c5 c2 c4 c3 c1 c0]
        int slot = (c & 0x60) | ((c & 4) << 2) | ((c & 0x18) >> 1) | (c & 3);
        float v = W1[e];
        int addr = slot * 512 + ((k * 2) ^ ((slot & 7) << 4));
        *(short*)(lds + addr) = f2bf(v);
    }
    // ---- stage W2^T (unpermuted) ----
    for (int e = tid; e < 16384; e += BLOCK) {   // W2 is [k][n], k<128, n<128
        int k = e >> 7, n = e & 127;
        float v = W2[e];
        int addr = 65536 + n * 256 + ((k * 2) ^ ((n & 7) << 4));
        *(short*)(lds + addr) = f2bf(v);
    }
    __syncthreads();

    const int wid   = tid >> 6;
    const int lane  = tid & 63;
    const int lrow  = lane & 15;   // edge row within tile / frag line
    const int lk8   = lane >> 4;   // k-subchunk 0..3
    const int hbase = 98304 + wid * 4096;
    const int rsw   = (lrow & 7) << 4;   // per-row LDS swizzle (tile + weights)

    // ---- persistent packed-bf16 constants (64 dwords) ----
    // b1 in GEMM1-chunk (q) order: col = (q>>1)*32 + lk8*8 + (q&1)*4 + i
    unsigned int ub1[16], ub2[16], ug[16], ubt[16];
    #pragma unroll
    for (int q = 0; q < 8; ++q) {
        const float* p = b1 + (q >> 1) * 32 + lk8 * 8 + (q & 1) * 4;
        ub1[q * 2 + 0] = pk2(p[0], p[1]);
        ub1[q * 2 + 1] = pk2(p[2], p[3]);
    }
    #pragma unroll
    for (int n2 = 0; n2 < 8; ++n2) {
        int c = n2 * 16 + lk8 * 4;
        ub2[n2 * 2 + 0] = pk2(b2[c], b2[c + 1]);
        ub2[n2 * 2 + 1] = pk2(b2[c + 2], b2[c + 3]);
        ug [n2 * 2 + 0] = pk2(gamma[c], gamma[c + 1]);
        ug [n2 * 2 + 1] = pk2(gamma[c + 2], gamma[c + 3]);
        ubt[n2 * 2 + 0] = pk2(beta[c], beta[c + 1]);
        ubt[n2 * 2 + 1] = pk2(beta[c + 2], beta[c + 3]);
    }

    const int ntiles  = (E + 15) >> 4;
    const int wstride = GRID * WAVES;

    int tile = blockIdx.x * WAVES + wid;
    if (tile >= ntiles) return;

    // ---- prologue: indices + staged gather for tile t; indices for t+1 ----
    int rowg = tile * 16 + lrow; if (rowg >= E) rowg = E - 1;
    int sidx = ei[rowg];
    int didx = ei[E + rowg];

    f32x4 Sn0, Sn1, Sn2, Sn3, Sn4, Sn5, Sn6, Sn7;   // node src/dst raw
    f32x4 Se0, Se1, Se2, Se3, Se4, Se5, Se6, Se7;   // edge row raw
    {
        const float* sp = node + (size_t)sidx * H_NODE + lk8 * 8;
        const float* dp = node + (size_t)didx * H_NODE + lk8 * 8;
        const float* ep = edgef + (size_t)rowg * H_EDGE + lk8 * 8;
        Sn0 = *(const f32x4*)(sp);      Sn1 = *(const f32x4*)(sp + 4);
        Sn2 = *(const f32x4*)(sp + 32); Sn3 = *(const f32x4*)(sp + 36);
        Sn4 = *(const f32x4*)(dp);      Sn5 = *(const f32x4*)(dp + 4);
        Sn6 = *(const f32x4*)(dp + 32); Sn7 = *(const f32x4*)(dp + 36);
        Se0 = *(const f32x4*)(ep);      Se1 = *(const f32x4*)(ep + 4);
        Se2 = *(const f32x4*)(ep + 32); Se3 = *(const f32x4*)(ep + 36);
        Se4 = *(const f32x4*)(ep + 64); Se5 = *(const f32x4*)(ep + 68);
        Se6 = *(const f32x4*)(ep + 96); Se7 = *(const f32x4*)(ep + 100);
    }
    int next  = tile + wstride;
    int nrowg = next * 16 + lrow; if (nrowg >= E) nrowg = E - 1;
    int nsidx = ei[nrowg];
    int ndidx = ei[E + nrowg];

    while (tile < ntiles) {
        const int r0 = tile * 16;

        // ---- fold staged gather (issued one full tile ago) into B-frags ----
        // (B-frag layout == old A-frag layout: lane holds in[r0+lrow][k=t*32+lk8*8+j])
        bf16x8 A1[8];
        A1[0] = cvt8(Sn0, Sn1);
        A1[1] = cvt8(Sn2, Sn3);
        A1[2] = cvt8(Sn4, Sn5);
        A1[3] = cvt8(Sn6, Sn7);
        A1[4] = cvt8(Se0, Se1);
        A1[5] = cvt8(Se2, Se3);
        A1[6] = cvt8(Se4, Se5);
        A1[7] = cvt8(Se6, Se7);

        // ---- park edge frags in per-wave tile for the residual ----
        #pragma unroll
        for (int t = 0; t < 4; ++t) {
            int wa = hbase + lrow * 256 + ((t * 64 + lk8 * 16) ^ rsw);
            *(bf16x8*)(lds + wa) = A1[4 + t];
        }

        // ---- issue NEXT tile's FULL gather burst (in flight all tile) ----
        {
            const float* sp = node + (size_t)nsidx * H_NODE + lk8 * 8;
            const float* dp = node + (size_t)ndidx * H_NODE + lk8 * 8;
            const float* ep = edgef + (size_t)nrowg * H_EDGE + lk8 * 8;
            Sn0 = *(const f32x4*)(sp);      Sn1 = *(const f32x4*)(sp + 4);
            Sn2 = *(const f32x4*)(sp + 32); Sn3 = *(const f32x4*)(sp + 36);
            Sn4 = *(const f32x4*)(dp);      Sn5 = *(const f32x4*)(dp + 4);
            Sn6 = *(const f32x4*)(dp + 32); Sn7 = *(const f32x4*)(dp + 36);
            Se0 = *(const f32x4*)(ep);      Se1 = *(const f32x4*)(ep + 4);
            Se2 = *(const f32x4*)(ep + 32); Se3 = *(const f32x4*)(ep + 36);
            Se4 = *(const f32x4*)(ep + 64); Se5 = *(const f32x4*)(ep + 68);
            Se6 = *(const f32x4*)(ep + 96); Se7 = *(const f32x4*)(ep + 100);
        }
        // ---- prefetch tile+2 indices ----
        int t2i = next + wstride;
        int t2rowg = t2i * 16 + lrow; if (t2rowg >= E) t2rowg = E - 1;
        int t2s = ei[t2rowg];
        int t2d = ei[E + t2rowg];

        // drain the 4 residual-tile writes (cheap; guarantees later reads see them)
        asm volatile("s_waitcnt lgkmcnt(0)" ::: "memory");

        // ---- GEMM1 (swapped): acc[q][i] = h_pre[r0+lrow][pi(q, lk8*4+i)] ----
        f32x4 acc[8];
        #pragma unroll
        for (int q = 0; q < 8; ++q) acc[q] = (f32x4){0.f, 0.f, 0.f, 0.f};
        #pragma unroll
        for (int q = 0; q < 8; ++q) {
            const int cb = (q * 16 + lrow) * 512;
            #pragma unroll
            for (int t = 0; t < 8; ++t) {
                int kb = t * 64 + lk8 * 16;
                bf16x8 wfrag = *(const bf16x8*)(lds + cb + (kb ^ rsw));
                acc[q] = __builtin_amdgcn_mfma_f32_16x16x32_bf16(wfrag, A1[t], acc[q], 0, 0, 0);
            }
        }

        // ---- bias1 + relu + pack: GEMM2 B-frags, fully lane-local ----
        // hf[t2][jj] = h[r0+lrow][t2*32 + lk8*8 + jj],  q = 2*t2 + (jj>>2)
        bf16x8 hf[4];
        #pragma unroll
        for (int t2 = 0; t2 < 4; ++t2) {
            #pragma unroll
            for (int h = 0; h < 2; ++h) {
                const int q = 2 * t2 + h;
                #pragma unroll
                for (int i = 0; i < 4; ++i) {
                    float b = upk(ub1[q * 2 + (i >> 1)], i & 1);
                    float v = fmaxf(acc[q][i] + b, 0.f);
                    hf[t2][h * 4 + i] = f2bf(v);
                }
            }
        }

        // ---- GEMM2 (swapped), reuse acc: acc[n2][i] = upd[r0+lrow][n2*16+lk8*4+i] ----
        #pragma unroll
        for (int n2 = 0; n2 < 8; ++n2) acc[n2] = (f32x4){0.f, 0.f, 0.f, 0.f};
        #pragma unroll
        for (int n2 = 0; n2 < 8; ++n2) {
            const int cb = 65536 + (n2 * 16 + lrow) * 256;
            #pragma unroll
            for (int t2 = 0; t2 < 4; ++t2) {
                int kb = t2 * 64 + lk8 * 16;
                bf16x8 wfrag = *(const bf16x8*)(lds + cb + (kb ^ rsw));
                acc[n2] = __builtin_amdgcn_mfma_f32_16x16x32_bf16(wfrag, hf[t2], acc[n2], 0, 0, 0);
            }
        }

        // ---- LayerNorm: row stats via 64 local + 2 shfl_xor pairs ----
        float s = 0.f, sq = 0.f;
        #pragma unroll
        for (int n2 = 0; n2 < 8; ++n2) {
            #pragma unroll
            for (int i = 0; i < 4; ++i) {
                float v = acc[n2][i] + upk(ub2[n2 * 2 + (i >> 1)], i & 1);
                s  += v;
                sq += v * v;
            }
        }
        s  += __shfl_xor(s,  16, 64);  s  += __shfl_xor(s,  32, 64);
        sq += __shfl_xor(sq, 16, 64);  sq += __shfl_xor(sq, 32, 64);
        float mu  = s * (1.f / 128.f);
        float var = sq * (1.f / 128.f) - mu * mu;
        float rs  = rsqrtf(var + LN_EPS);

        // ---- residual from per-wave tile + direct f32 store ----
        {
            int row = r0 + lrow;
            if (row < E) {
                float* orow = out + (size_t)row * H_EDGE;
                #pragma unroll
                for (int n2 = 0; n2 < 8; ++n2) {
                    int ra = hbase + lrow * 256 + ((n2 * 32 + lk8 * 8) ^ rsw);
                    bf16x4 rv = *(const bf16x4*)(lds + ra);
                    float4 w4;
                    #pragma unroll
                    for (int i = 0; i < 4; ++i) {
                        float u2 = acc[n2][i] + upk(ub2[n2 * 2 + (i >> 1)], i & 1);
                        float w  = (u2 - mu) * rs * upk(ug[n2 * 2 + (i >> 1)], i & 1)
                                 + upk(ubt[n2 * 2 + (i >> 1)], i & 1) + bf2f(rv[i]);
                        ((float*)&w4)[i] = w;
                    }
                    *(float4*)(orow + n2 * 16 + lk8 * 4) = w4;
                }
            }
        }

        // ---- rotate pipeline state ----
        tile = next;  next = t2i;
        nrowg = t2rowg; nsidx = t2s; ndidx = t2d;
    }
}

extern "C" void kernel_launch(void* const* d_in, const int* in_sizes, int n_in,
                              void* d_out, int out_size, void* d_ws, size_t ws_size,
                              hipStream_t stream) {
    const float* node  = (const float*)d_in[0];
    const float* edgef = (const float*)d_in[1];
    const int*   ei    = (const int*)d_in[2];    // int32 on device
    const float* W1    = (const float*)d_in[3];
    const float* b1    = (const float*)d_in[4];
    const float* W2    = (const float*)d_in[5];
    const float* b2    = (const float*)d_in[6];
    const float* gamma = (const float*)d_in[7];
    const float* beta  = (const float*)d_in[8];
    float* outp = (float*)d_out;
    const int E = in_sizes[2] / 2;   // edge_index is [2, E]

    hipLaunchKernelGGL(edge_update, dim3(GRID), dim3(BLOCK), 0, stream,
                       node, edgef, ei, W1, b1, W2, b2, gamma, beta, outp, E);
}